// Round 2
// baseline (3077.480 us; speedup 1.0000x reference)
//
#include <hip/hip_runtime.h>
#include <math.h>

// Problem constants: B=256, TQ=64, N=196, E=1024, K=512
// FLOP budget ~188 GF fp32 -> VALU-bound (no fp32 MFMA on CDNA4), floor ~1.2ms @157TF.

__device__ __forceinline__ float fast_tanh(float x) {
    float ax = fabsf(x);
    float e  = __expf(-2.0f * ax);
    float r  = (1.0f - e) / (1.0f + e);
    return copysignf(r, x);
}

// Generic tiled fp32 GEMM:
//   C[b,m,n] = ACT( sum_k A[b,m,k]*B[b,k,n] + bias[n] + D[b,m,n] )
// A addr = br*ab + r*am + k*ak
//   ALOAD=0 (AKF): ak==1, float4 along k
//   ALOAD=1 (AMF): am==1, float4 along m (requires M%4==0 per-batch alignment; true here)
// B addr = bz*bb + k*bk + n*bn
//   BLOAD=0 (BNF): bn==1, float4 along n
//   BLOAD=1 (BKF): bk==1, float4 along k (transpose store)
// C/D addr = br*cb + r*cm + n
// BATCHED: br = blockIdx.z. Else folded rows: br = gm/NBF, r = gm%NBF (NBF==0 -> br=0).
template<int BM,int BN,int BK,int TM,int TN,int ALOAD,int BLOAD,int NBF,int ACT,bool BATCHED>
__global__ __launch_bounds__(256) void gemm_k(
    const float* __restrict__ A, const float* __restrict__ Bm,
    const float* __restrict__ bias, const float* __restrict__ Dadd,
    float* __restrict__ C,
    const int M, const int Nn, const int K,
    const int ab, const int am, const int ak,
    const int bb, const int bk, const int bn,
    const int cb, const int cm)
{
    static_assert(BK == 16, "staging math assumes BK==16");
    __shared__ __align__(16) float As[BK][BM + 4];
    __shared__ __align__(16) float Bs[BK][BN + 4];

    const int t  = threadIdx.x;
    const int n0 = blockIdx.x * BN;
    const int m0 = blockIdx.y * BM;
    const int bz = BATCHED ? blockIdx.z : 0;
    const int w  = t >> 6;        // wave id 0..3 (2x2 quadrants)
    const int l  = t & 63;
    const int tx = l & 7, ty = l >> 3;   // 8x8 lanes in wave
    const int mloc = (w >> 1) * (BM / 2) + ty * TM;
    const int nloc = (w & 1)  * (BN / 2) + tx * TN;

    float acc[TM][TN];
    #pragma unroll
    for (int i = 0; i < TM; ++i)
        #pragma unroll
        for (int j = 0; j < TN; ++j) acc[i][j] = 0.f;

    for (int k0 = 0; k0 < K; k0 += BK) {
        // ---------------- stage A ----------------
        if (ALOAD == 0) {   // float4 along k
            constexpr int NF4 = (BM * BK) / (4 * 256);
            #pragma unroll
            for (int i = 0; i < NF4; ++i) {
                int f4i = i * 256 + t;
                int row = f4i >> 2;            // / (BK/4)
                int kq  = (f4i & 3) << 2;
                int gm = m0 + row, gk = k0 + kq;
                float4 v = make_float4(0.f, 0.f, 0.f, 0.f);
                if (gm < M) {
                    int br, r;
                    if (BATCHED)      { br = bz; r = gm; }
                    else if (NBF > 0) { br = gm / NBF; r = gm - br * NBF; }
                    else              { br = 0;  r = gm; }
                    const float* p = A + (size_t)br * ab + (size_t)r * am + gk; // ak==1
                    if (gk + 4 <= K) v = *(const float4*)p;
                    else {
                        float tv[4] = {0.f, 0.f, 0.f, 0.f};
                        #pragma unroll
                        for (int j = 0; j < 4; ++j) if (gk + j < K) tv[j] = p[j];
                        v = make_float4(tv[0], tv[1], tv[2], tv[3]);
                    }
                }
                As[kq + 0][row] = v.x; As[kq + 1][row] = v.y;
                As[kq + 2][row] = v.z; As[kq + 3][row] = v.w;
            }
        } else {            // AMF: float4 along m (unit stride), vector LDS write
            constexpr int NF4 = (BM * BK) / (4 * 256);
            #pragma unroll
            for (int i = 0; i < NF4; ++i) {
                int f4i = i * 256 + t;
                int m4 = f4i % (BM / 4);
                int kk = f4i / (BM / 4);
                int gm = m0 + m4 * 4, gk = k0 + kk;
                float4 v = make_float4(0.f, 0.f, 0.f, 0.f);
                if (gm < M && gk < K) {
                    int br, r;
                    if (BATCHED)      { br = bz; r = gm; }
                    else if (NBF > 0) { br = gm / NBF; r = gm - br * NBF; }
                    else              { br = 0;  r = gm; }
                    // am==1; 4 consecutive m stay in one batch (NBF%4==0, M%4==0)
                    const float* p = A + (size_t)br * ab + (size_t)r + (size_t)gk * ak;
                    v = *(const float4*)p;
                }
                *(float4*)&As[kk][m4 * 4] = v;
            }
        }
        // ---------------- stage B ----------------
        if (BLOAD == 0) {   // float4 along n
            constexpr int NF4 = (BK * BN) / (4 * 256);
            #pragma unroll
            for (int i = 0; i < NF4; ++i) {
                int f4i = i * 256 + t;
                int nq = f4i % (BN / 4);
                int kk = f4i / (BN / 4);
                int gn = n0 + nq * 4, gk = k0 + kk;
                float4 v = make_float4(0.f, 0.f, 0.f, 0.f);
                if (gk < K && gn + 4 <= Nn) {
                    const float* p = Bm + (size_t)bz * bb + (size_t)gk * bk + gn; // bn==1
                    v = *(const float4*)p;
                }
                *(float4*)&Bs[kk][nq * 4] = v;
            }
        } else {            // BKF: float4 along k, transpose store
            constexpr int NF4 = (BK * BN) / (4 * 256);
            #pragma unroll
            for (int i = 0; i < NF4; ++i) {
                int f4i = i * 256 + t;
                int col = f4i >> 2;            // / (BK/4)
                int kq  = (f4i & 3) << 2;
                int gn = n0 + col, gk = k0 + kq;
                float4 v = make_float4(0.f, 0.f, 0.f, 0.f);
                if (gn < Nn) {
                    const float* p = Bm + (size_t)bz * bb + (size_t)gn * bn + gk; // bk==1
                    if (gk + 4 <= K) v = *(const float4*)p;
                    else {
                        float tv[4] = {0.f, 0.f, 0.f, 0.f};
                        #pragma unroll
                        for (int j = 0; j < 4; ++j) if (gk + j < K) tv[j] = p[j];
                        v = make_float4(tv[0], tv[1], tv[2], tv[3]);
                    }
                }
                Bs[kq + 0][col] = v.x; Bs[kq + 1][col] = v.y;
                Bs[kq + 2][col] = v.z; Bs[kq + 3][col] = v.w;
            }
        }
        __syncthreads();
        // ---------------- compute ----------------
        #pragma unroll
        for (int kk = 0; kk < BK; ++kk) {
            float a[TM], b[TN];
            #pragma unroll
            for (int i = 0; i < TM; i += 4)
                *(float4*)&a[i] = *(const float4*)&As[kk][mloc + i];
            #pragma unroll
            for (int j = 0; j < TN; j += 4)
                *(float4*)&b[j] = *(const float4*)&Bs[kk][nloc + j];
            #pragma unroll
            for (int i = 0; i < TM; ++i)
                #pragma unroll
                for (int j = 0; j < TN; ++j)
                    acc[i][j] = fmaf(a[i], b[j], acc[i][j]);
        }
        __syncthreads();
    }
    // ---------------- epilogue ----------------
    #pragma unroll
    for (int i = 0; i < TM; ++i) {
        int gm = m0 + mloc + i;
        if (gm >= M) continue;
        int br, r;
        if (BATCHED)      { br = bz; r = gm; }
        else if (NBF > 0) { br = gm / NBF; r = gm - br * NBF; }
        else              { br = 0;  r = gm; }
        const size_t crow = (size_t)br * cb + (size_t)r * cm;
        #pragma unroll
        for (int j = 0; j < TN; ++j) {
            int gn = n0 + nloc + j;
            if (gn >= Nn) continue;
            float v = acc[i][j];
            if (bias) v += bias[gn];
            size_t ci = crow + gn;
            if (Dadd) v += Dadd[ci];
            if (ACT == 1) v = fast_tanh(v);
            C[ci] = v;
        }
    }
}

// img branch tail: score = img_h . wia + bia ; softmax over n ; out = sum_n att*img_t
__global__ __launch_bounds__(256) void img_branch_kernel(
    const float* __restrict__ ih,       // [CB,196,512] tanh'd hidden (chunk-local)
    const float* __restrict__ wia, const float* __restrict__ bia,
    const float* __restrict__ img_feat, // [CB,1024,196]
    float* __restrict__ out)            // [CB,1024]
{
    const int b = blockIdx.x;
    const int t = threadIdx.x;
    const int w = t >> 6, l = t & 63;
    __shared__ float s_w[512];
    __shared__ __align__(16) float sc[200];
    __shared__ float red[8];

    for (int i = t; i < 512; i += 256) s_w[i] = wia[i];
    __syncthreads();

    const float* ihb = ih + (size_t)b * 196 * 512;
    for (int n = w; n < 196; n += 4) {
        const float* row = ihb + n * 512;
        float p = 0.f;
        for (int k = l; k < 512; k += 64) p = fmaf(s_w[k], row[k], p);
        #pragma unroll
        for (int off = 32; off > 0; off >>= 1) p += __shfl_xor(p, off);
        if (l == 0) sc[n] = p + bia[0];
    }
    __syncthreads();

    float v = (t < 196) ? sc[t] : -3.402823466e38f;
    float m = v;
    #pragma unroll
    for (int off = 32; off > 0; off >>= 1) m = fmaxf(m, __shfl_xor(m, off));
    if (l == 0) red[w] = m;
    __syncthreads();
    if (t == 0) {
        float mm = red[0];
        for (int i = 1; i < 4; ++i) mm = fmaxf(mm, red[i]);
        red[4] = mm;
    }
    __syncthreads();
    float mx = red[4];
    float e = (t < 196) ? __expf(v - mx) : 0.f;
    float s = e;
    #pragma unroll
    for (int off = 32; off > 0; off >>= 1) s += __shfl_xor(s, off);
    if (l == 0) red[w] = s;
    __syncthreads();
    if (t == 0) red[5] = 1.f / (red[0] + red[1] + red[2] + red[3]);
    __syncthreads();
    if (t < 196) sc[t] = e * red[5];
    __syncthreads();

    // out[b,e] = sum_n att[n] * img_feat[b,e,n]  (rows contiguous in n, float4)
    const float* ifb = img_feat + (size_t)b * 1024 * 196;
    for (int e0 = t; e0 < 1024; e0 += 256) {
        const float4* row = (const float4*)(ifb + (size_t)e0 * 196);
        float acc = 0.f;
        #pragma unroll 7
        for (int n4 = 0; n4 < 49; ++n4) {
            float4 x = row[n4];
            float4 a = *(const float4*)&sc[n4 * 4];
            acc = fmaf(x.x, a.x, acc);
            acc = fmaf(x.y, a.y, acc);
            acc = fmaf(x.z, a.z, acc);
            acc = fmaf(x.w, a.w, acc);
        }
        out[(size_t)b * 1024 + e0] = acc;
    }
}

// ques branch tail: score = (ques_h . wqa + bqa)*mask ; softmax over 64 ; out = sum_q att*Q
__global__ __launch_bounds__(256) void ques_branch_kernel(
    const float* __restrict__ qh,   // [CB,64,512]
    const float* __restrict__ wqa, const float* __restrict__ bqa,
    const float* __restrict__ mask, // [CB,64]
    const float* __restrict__ qf,   // [CB,64,1024]
    float* __restrict__ out)        // [CB,1024]
{
    const int b = blockIdx.x;
    const int t = threadIdx.x;
    const int w = t >> 6, l = t & 63;
    __shared__ float s_w[512];
    __shared__ float sq[64];

    for (int i = t; i < 512; i += 256) s_w[i] = wqa[i];
    __syncthreads();

    const float* qhb = qh + (size_t)b * 64 * 512;
    for (int q = w; q < 64; q += 4) {
        const float* row = qhb + q * 512;
        float p = 0.f;
        for (int k = l; k < 512; k += 64) p = fmaf(s_w[k], row[k], p);
        #pragma unroll
        for (int off = 32; off > 0; off >>= 1) p += __shfl_xor(p, off);
        if (l == 0) sq[q] = (p + bqa[0]) * mask[b * 64 + q];
    }
    __syncthreads();

    if (w == 0) {
        float v = sq[l];
        float m = v;
        #pragma unroll
        for (int off = 32; off > 0; off >>= 1) m = fmaxf(m, __shfl_xor(m, off));
        float e = __expf(v - m);
        float s = e;
        #pragma unroll
        for (int off = 32; off > 0; off >>= 1) s += __shfl_xor(s, off);
        sq[l] = e / s;
    }
    __syncthreads();

    const float* qfb = qf + (size_t)b * 64 * 1024;
    float4 acc = make_float4(0.f, 0.f, 0.f, 0.f);
    for (int q = 0; q < 64; ++q) {
        float a = sq[q];
        float4 x = *(const float4*)(qfb + q * 1024 + t * 4);
        acc.x = fmaf(a, x.x, acc.x);
        acc.y = fmaf(a, x.y, acc.y);
        acc.z = fmaf(a, x.z, acc.z);
        acc.w = fmaf(a, x.w, acc.w);
    }
    *(float4*)(out + (size_t)b * 1024 + t * 4) = acc;
}

extern "C" void kernel_launch(void* const* d_in, const int* in_sizes, int n_in,
                              void* d_out, int out_size, void* d_ws, size_t ws_size,
                              hipStream_t stream) {
    const float* qf  = (const float*)d_in[0];   // [256,64,1024]
    const float* imf = (const float*)d_in[1];   // [256,1024,196]
    const float* msk = (const float*)d_in[2];   // [256,64]
    const float* Wc  = (const float*)d_in[3];   // [1024,1024]
    const float* bc  = (const float*)d_in[4];
    const float* Wq  = (const float*)d_in[5];   // [1024,512]
    const float* bq  = (const float*)d_in[6];
    const float* Wi  = (const float*)d_in[7];   // [1024,512]
    const float* bi  = (const float*)d_in[8];
    const float* wqa = (const float*)d_in[9];   // [512]
    const float* bqa = (const float*)d_in[10];  // scalar
    const float* wia = (const float*)d_in[11];  // [512]
    const float* bia = (const float*)d_in[12];  // scalar
    float* out = (float*)d_out;

    // Per-batch workspace floats: qe 32768 + ic 200704 + ie 100352 + wt 12544 + qh 32768
    const size_t perBatchF = 379136ull;
    // Largest power-of-two chunk of batches that fits ws_size (constant across calls).
    int CB = 256;
    while (CB > 1 && (size_t)CB * perBatchF * 4ull > ws_size) CB >>= 1;

    float* ws = (float*)d_ws;
    float* qe = ws;                                   // [CB,64,512]
    float* ic = qe + (size_t)CB * 32768;              // [CB,196,1024] (reused as img_h [CB,196,512])
    float* ie = ic + (size_t)CB * 200704;             // [CB,196,512]
    float* wt = ie + (size_t)CB * 100352;             // [CB,64,196]
    float* qh = wt + (size_t)CB * 12544;              // [CB,64,512]

    dim3 blk(256);
    auto cdiv = [](int a, int b) { return (a + b - 1) / b; };

    for (int c0 = 0; c0 < 256; c0 += CB) {
        const float* qfc  = qf  + (size_t)c0 * 65536;
        const float* imfc = imf + (size_t)c0 * 200704;
        const float* mskc = msk + (size_t)c0 * 64;
        float* outq = out + (size_t)c0 * 1024;
        float* outi = out + 262144 + (size_t)c0 * 1024;

        // G1: ques_embed = Q @ Wq + bq      (M=CB*64, N=512, K=1024; flat rows)
        hipLaunchKernelGGL((gemm_k<128,128,16,8,8,0,0,0,0,false>),
            dim3(4, cdiv(CB * 64, 128), 1), blk, 0, stream,
            qfc, Wq, bq, (const float*)nullptr, qe,
            CB * 64, 512, 1024,  0,1024,1,  0,512,1,  0,512);

        // G2: img_corr[b,n,e'] = img_t @ Wc + bc   (M=CB*196 folded, AMF staging)
        hipLaunchKernelGGL((gemm_k<128,128,16,8,8,1,0,196,0,false>),
            dim3(8, cdiv(CB * 196, 128), 1), blk, 0, stream,
            imfc, Wc, bc, (const float*)nullptr, ic,
            CB * 196, 1024, 1024,  200704,1,196,  0,1024,1,  200704,1024);

        // G3: img_embed = img_t @ Wi + bi
        hipLaunchKernelGGL((gemm_k<128,128,16,8,8,1,0,196,0,false>),
            dim3(4, cdiv(CB * 196, 128), 1), blk, 0, stream,
            imfc, Wi, bi, (const float*)nullptr, ie,
            CB * 196, 512, 1024,  200704,1,196,  0,512,1,  100352,512);

        // G4: weight[b,q,n] = tanh(Q @ img_corr^T)   batched NT
        hipLaunchKernelGGL((gemm_k<64,64,16,4,4,0,1,0,1,true>),
            dim3(4, 1, CB), blk, 0, stream,
            qfc, ic, (const float*)nullptr, (const float*)nullptr, wt,
            64, 196, 1024,  65536,1024,1,  200704,1,1024,  12544,196);

        // G5a: img_h[b,n,k] = tanh(weight^T @ qe + img_embed)   (writes into ic buffer)
        hipLaunchKernelGGL((gemm_k<128,128,16,8,8,1,0,0,1,true>),
            dim3(4, 2, CB), blk, 0, stream,
            wt, qe, (const float*)nullptr, ie, ic,
            196, 512, 64,  12544,1,196,  32768,512,1,  100352,512);

        // G5b: img score -> softmax -> img_atten_feat
        hipLaunchKernelGGL(img_branch_kernel, dim3(CB), blk, 0, stream,
            ic, wia, bia, imfc, outi);

        // G6a: ques_h[b,q,k] = tanh(weight @ img_embed + qe)
        hipLaunchKernelGGL((gemm_k<64,64,16,4,4,0,0,0,1,true>),
            dim3(8, 1, CB), blk, 0, stream,
            wt, ie, (const float*)nullptr, qe, qh,
            64, 512, 196,  12544,196,1,  100352,512,1,  32768,512);

        // G6b: ques score -> mask -> softmax -> ques_atten_feat
        hipLaunchKernelGGL(ques_branch_kernel, dim3(CB), blk, 0, stream,
            qh, wqa, bqa, mskc, qfc, outq);
    }
}

// Round 4
// 1683.276 us; speedup vs baseline: 1.8283x; 1.8283x over previous
//
#include <hip/hip_runtime.h>
#include <math.h>

// Problem constants: B=256, TQ=64, N=196, E=1024, K=512
// 188 GF total; G1/G2/G3 (175 GF) on bf16 MFMA w/ hi/lo split (error ~2^-17),
// rest fp32 vector. No fp32-input MFMA on CDNA4.

typedef float f32x4 __attribute__((ext_vector_type(4)));
typedef short bf16x8 __attribute__((ext_vector_type(8)));

__device__ __forceinline__ float fast_tanh(float x) {
    float ax = fabsf(x);
    float e  = __expf(-2.0f * ax);
    float r  = (1.0f - e) / (1.0f + e);
    return copysignf(r, x);
}

__device__ __forceinline__ unsigned short f2bf(float f) {
    unsigned u = __float_as_uint(f);
    u += 0x7FFF + ((u >> 16) & 1);          // RNE
    return (unsigned short)(u >> 16);
}
__device__ __forceinline__ void split_hl(float f, unsigned short &h, unsigned short &l) {
    h = f2bf(f);
    float fh = __uint_as_float((unsigned)h << 16);
    l = f2bf(f - fh);
}
__device__ __forceinline__ void st4(unsigned short* s, int idx,
                                    unsigned short a, unsigned short b,
                                    unsigned short c, unsigned short d) {
    uint2 w;
    w.x = (unsigned)a | ((unsigned)b << 16);
    w.y = (unsigned)c | ((unsigned)d << 16);
    *(uint2*)(s + idx) = w;   // idx%4==0 -> 8B aligned
}

// ---------------------------------------------------------------------------
// MFMA GEMM: C[m,n] = sum_k A[m,k]*B[k,n] + bias[n], fp32 in/out, bf16 hi/lo
// split internally (3 MFMAs per product: hh + hl + lh; err ~2^-17 rel).
// NBF==0: A row-major [M,K] (k-contiguous, row stride lda).
// NBF>0 : A folded img layout: addr = (m/NBF)*ab + k*NBF + (m%NBF)  (m-contig).
// Block: 128x128, 4 waves (2x2 of 64x64), K-step 32.
// LDS layout: per 16-row panel: 2 planes (hi,lo) x 64 lane-slots x 16B,
//   plane stride 1040B (pad 16B to de-alias banks), panel stride 2080B.
//   slot lane = perm(row&15) + 16*(k>>3), bytes j=(k&7)*2.
//   perm(s) = ((s&3)<<2)|(s>>2) (involution) -> transpose-staging writes dense.
// Epilogue mapping: logical row off = 4*i + (lane>>4), col off = perm(lane&15).
// ---------------------------------------------------------------------------
template<int NBF>
__global__ __launch_bounds__(256) void mfma_gemm(
    const float* __restrict__ A, const float* __restrict__ Bw,
    const float* __restrict__ bias, float* __restrict__ C,
    const int M, const int N, const int K,
    const int lda, const int ab)
{
    __shared__ __align__(16) unsigned short smem[16640];   // 33,280 B
    unsigned short* As = smem;                  // 8 panels * 1040 ushort
    unsigned short* Bs = smem + 8320;

    const int t  = threadIdx.x;
    const int n0 = blockIdx.x * 128;
    const int m0 = blockIdx.y * 128;
    const int wid = t >> 6, l = t & 63;
    const int wm = wid >> 1, wn = wid & 1;

    f32x4 acc[4][4];
    #pragma unroll
    for (int p = 0; p < 4; ++p)
        #pragma unroll
        for (int q = 0; q < 4; ++q)
            acc[p][q] = (f32x4){0.f, 0.f, 0.f, 0.f};

    // --- staging precompute ---
    // A (NBF>0): thread owns 4m x 4k block
    const int mq  = (t & 31) << 2;
    const int kqa = (t >> 5) << 2;
    const float* baseA = nullptr;
    bool avalid = true;
    if (NBF > 0) {
        int gm0 = m0 + mq;
        avalid = (gm0 < M);
        int br = gm0 / NBF;
        int r0 = gm0 - br * NBF;
        baseA = A + (size_t)br * ab + r0 + (size_t)kqa * NBF;
    }
    int idxA[4];
    if (NBF > 0) {
        #pragma unroll
        for (int c = 0; c < 4; ++c) {
            int lr = mq + c;            // local row 0..127
            int sr = ((lr & 3) << 2) | ((lr & 15) >> 2);
            idxA[c] = (lr >> 4) * 1040 + (sr + ((kqa >> 3) << 4)) * 8 + (kqa & 7);
        }
    }
    // B: thread owns 4k x 4n block (transpose)
    const int kqb = kqa;                 // same decomposition
    const int nq  = mq;
    const float* baseB = Bw + (size_t)kqb * N + n0 + nq;
    int idxB[4];
    #pragma unroll
    for (int c = 0; c < 4; ++c) {
        int lc = nq + c;
        int sc = ((lc & 3) << 2) | ((lc & 15) >> 2);
        idxB[c] = (lc >> 4) * 1040 + (sc + ((kqb >> 3) << 4)) * 8 + (kqb & 7);
    }

    const int nk = K >> 5;
    for (int ks = 0; ks < nk; ++ks) {
        const int k0 = ks << 5;
        // ---------------- stage A ----------------
        if (NBF > 0) {
            float4 v[4];
            if (avalid) {
                const float* p = baseA + (size_t)k0 * NBF;
                #pragma unroll
                for (int i = 0; i < 4; ++i) v[i] = *(const float4*)(p + (size_t)i * NBF);
            } else {
                #pragma unroll
                for (int i = 0; i < 4; ++i) v[i] = make_float4(0.f, 0.f, 0.f, 0.f);
            }
            const float* vf = (const float*)v;
            #pragma unroll
            for (int c = 0; c < 4; ++c) {
                unsigned short h[4], lo[4];
                #pragma unroll
                for (int i = 0; i < 4; ++i) split_hl(vf[i * 4 + c], h[i], lo[i]);
                st4(As, idxA[c],       h[0],  h[1],  h[2],  h[3]);
                st4(As, idxA[c] + 520, lo[0], lo[1], lo[2], lo[3]);
            }
        } else {
            #pragma unroll
            for (int i = 0; i < 4; ++i) {
                int f4i = i * 256 + t;
                int row = f4i >> 3;
                int kq  = (f4i & 7) << 2;
                int gm  = m0 + row;
                float4 v = make_float4(0.f, 0.f, 0.f, 0.f);
                if (gm < M) v = *(const float4*)(A + (size_t)gm * lda + k0 + kq);
                unsigned short h[4], lo[4];
                split_hl(v.x, h[0], lo[0]); split_hl(v.y, h[1], lo[1]);
                split_hl(v.z, h[2], lo[2]); split_hl(v.w, h[3], lo[3]);
                int sr = ((row & 3) << 2) | ((row & 15) >> 2);
                int idx = (row >> 4) * 1040 + (sr + ((kq >> 3) << 4)) * 8 + (kq & 7);
                st4(As, idx,       h[0],  h[1],  h[2],  h[3]);
                st4(As, idx + 520, lo[0], lo[1], lo[2], lo[3]);
            }
        }
        // ---------------- stage B (4k x 4n transpose) ----------------
        {
            const float* p = baseB + (size_t)k0 * N;
            float4 v[4];
            #pragma unroll
            for (int i = 0; i < 4; ++i) v[i] = *(const float4*)(p + (size_t)i * N);
            const float* vf = (const float*)v;
            #pragma unroll
            for (int c = 0; c < 4; ++c) {
                unsigned short h[4], lo[4];
                #pragma unroll
                for (int i = 0; i < 4; ++i) split_hl(vf[i * 4 + c], h[i], lo[i]);
                st4(Bs, idxB[c],       h[0],  h[1],  h[2],  h[3]);
                st4(Bs, idxB[c] + 520, lo[0], lo[1], lo[2], lo[3]);
            }
        }
        __syncthreads();
        // ---------------- compute ----------------
        bf16x8 ah[4], al[4], bh[4], bl[4];
        #pragma unroll
        for (int p = 0; p < 4; ++p) {
            const unsigned short* pa = As + (wm * 4 + p) * 1040 + l * 8;
            ah[p] = *(const bf16x8*)pa;
            al[p] = *(const bf16x8*)(pa + 520);
        }
        #pragma unroll
        for (int q = 0; q < 4; ++q) {
            const unsigned short* pb = Bs + (wn * 4 + q) * 1040 + l * 8;
            bh[q] = *(const bf16x8*)pb;
            bl[q] = *(const bf16x8*)(pb + 520);
        }
        #pragma unroll
        for (int p = 0; p < 4; ++p)
            #pragma unroll
            for (int q = 0; q < 4; ++q)
                acc[p][q] = __builtin_amdgcn_mfma_f32_16x16x32_bf16(ah[p], bh[q], acc[p][q], 0, 0, 0);
        #pragma unroll
        for (int p = 0; p < 4; ++p)
            #pragma unroll
            for (int q = 0; q < 4; ++q)
                acc[p][q] = __builtin_amdgcn_mfma_f32_16x16x32_bf16(ah[p], bl[q], acc[p][q], 0, 0, 0);
        #pragma unroll
        for (int p = 0; p < 4; ++p)
            #pragma unroll
            for (int q = 0; q < 4; ++q)
                acc[p][q] = __builtin_amdgcn_mfma_f32_16x16x32_bf16(al[p], bh[q], acc[p][q], 0, 0, 0);
        __syncthreads();
    }
    // ---------------- epilogue ----------------
    const int colp = ((l & 3) << 2) | ((l & 15) >> 2);   // perm(l&15)
    #pragma unroll
    for (int q = 0; q < 4; ++q) {
        int col = n0 + wn * 64 + q * 16 + colp;
        float bv = bias[col];
        #pragma unroll
        for (int p = 0; p < 4; ++p) {
            int rbase = m0 + wm * 64 + p * 16 + (l >> 4);
            #pragma unroll
            for (int i = 0; i < 4; ++i) {
                int row = rbase + 4 * i;
                if (row < M) C[(size_t)row * N + col] = acc[p][q][i] + bv;
            }
        }
    }
}

// ---------------------------------------------------------------------------
// fp32 vector GEMM (kept for the small einsums G4/G5a/G6a)
// ---------------------------------------------------------------------------
template<int BM,int BN,int BK,int TM,int TN,int ALOAD,int BLOAD,int NBF,int ACT,bool BATCHED>
__global__ __launch_bounds__(256) void gemm_k(
    const float* __restrict__ A, const float* __restrict__ Bm,
    const float* __restrict__ bias, const float* __restrict__ Dadd,
    float* __restrict__ C,
    const int M, const int Nn, const int K,
    const int ab, const int am, const int ak,
    const int bb, const int bk, const int bn,
    const int cb, const int cm)
{
    static_assert(BK == 16, "staging math assumes BK==16");
    __shared__ __align__(16) float As[BK][BM + 4];
    __shared__ __align__(16) float Bs[BK][BN + 4];

    const int t  = threadIdx.x;
    const int n0 = blockIdx.x * BN;
    const int m0 = blockIdx.y * BM;
    const int bz = BATCHED ? blockIdx.z : 0;
    const int w  = t >> 6;
    const int l  = t & 63;
    const int tx = l & 7, ty = l >> 3;
    const int mloc = (w >> 1) * (BM / 2) + ty * TM;
    const int nloc = (w & 1)  * (BN / 2) + tx * TN;

    float acc[TM][TN];
    #pragma unroll
    for (int i = 0; i < TM; ++i)
        #pragma unroll
        for (int j = 0; j < TN; ++j) acc[i][j] = 0.f;

    for (int k0 = 0; k0 < K; k0 += BK) {
        if (ALOAD == 0) {
            constexpr int NF4 = (BM * BK) / (4 * 256);
            #pragma unroll
            for (int i = 0; i < NF4; ++i) {
                int f4i = i * 256 + t;
                int row = f4i >> 2;
                int kq  = (f4i & 3) << 2;
                int gm = m0 + row, gk = k0 + kq;
                float4 v = make_float4(0.f, 0.f, 0.f, 0.f);
                if (gm < M) {
                    int br, r;
                    if (BATCHED)      { br = bz; r = gm; }
                    else if (NBF > 0) { br = gm / NBF; r = gm - br * NBF; }
                    else              { br = 0;  r = gm; }
                    const float* p = A + (size_t)br * ab + (size_t)r * am + gk;
                    if (gk + 4 <= K) v = *(const float4*)p;
                    else {
                        float tv[4] = {0.f, 0.f, 0.f, 0.f};
                        #pragma unroll
                        for (int j = 0; j < 4; ++j) if (gk + j < K) tv[j] = p[j];
                        v = make_float4(tv[0], tv[1], tv[2], tv[3]);
                    }
                }
                As[kq + 0][row] = v.x; As[kq + 1][row] = v.y;
                As[kq + 2][row] = v.z; As[kq + 3][row] = v.w;
            }
        } else {
            constexpr int NF4 = (BM * BK) / (4 * 256);
            #pragma unroll
            for (int i = 0; i < NF4; ++i) {
                int f4i = i * 256 + t;
                int m4 = f4i % (BM / 4);
                int kk = f4i / (BM / 4);
                int gm = m0 + m4 * 4, gk = k0 + kk;
                float4 v = make_float4(0.f, 0.f, 0.f, 0.f);
                if (gm < M && gk < K) {
                    int br, r;
                    if (BATCHED)      { br = bz; r = gm; }
                    else if (NBF > 0) { br = gm / NBF; r = gm - br * NBF; }
                    else              { br = 0;  r = gm; }
                    const float* p = A + (size_t)br * ab + (size_t)r + (size_t)gk * ak;
                    v = *(const float4*)p;
                }
                *(float4*)&As[kk][m4 * 4] = v;
            }
        }
        if (BLOAD == 0) {
            constexpr int NF4 = (BK * BN) / (4 * 256);
            #pragma unroll
            for (int i = 0; i < NF4; ++i) {
                int f4i = i * 256 + t;
                int nq2 = f4i % (BN / 4);
                int kk = f4i / (BN / 4);
                int gn = n0 + nq2 * 4, gk = k0 + kk;
                float4 v = make_float4(0.f, 0.f, 0.f, 0.f);
                if (gk < K && gn + 4 <= Nn) {
                    const float* p = Bm + (size_t)bz * bb + (size_t)gk * bk + gn;
                    v = *(const float4*)p;
                }
                *(float4*)&Bs[kk][nq2 * 4] = v;
            }
        } else {
            constexpr int NF4 = (BK * BN) / (4 * 256);
            #pragma unroll
            for (int i = 0; i < NF4; ++i) {
                int f4i = i * 256 + t;
                int col = f4i >> 2;
                int kq  = (f4i & 3) << 2;
                int gn = n0 + col, gk = k0 + kq;
                float4 v = make_float4(0.f, 0.f, 0.f, 0.f);
                if (gn < Nn) {
                    const float* p = Bm + (size_t)bz * bb + (size_t)gn * bn + gk;
                    if (gk + 4 <= K) v = *(const float4*)p;
                    else {
                        float tv[4] = {0.f, 0.f, 0.f, 0.f};
                        #pragma unroll
                        for (int j = 0; j < 4; ++j) if (gk + j < K) tv[j] = p[j];
                        v = make_float4(tv[0], tv[1], tv[2], tv[3]);
                    }
                }
                Bs[kq + 0][col] = v.x; Bs[kq + 1][col] = v.y;
                Bs[kq + 2][col] = v.z; Bs[kq + 3][col] = v.w;
            }
        }
        __syncthreads();
        #pragma unroll
        for (int kk = 0; kk < BK; ++kk) {
            float a[TM], b[TN];
            #pragma unroll
            for (int i = 0; i < TM; i += 4)
                *(float4*)&a[i] = *(const float4*)&As[kk][mloc + i];
            #pragma unroll
            for (int j = 0; j < TN; j += 4)
                *(float4*)&b[j] = *(const float4*)&Bs[kk][nloc + j];
            #pragma unroll
            for (int i = 0; i < TM; ++i)
                #pragma unroll
                for (int j = 0; j < TN; ++j)
                    acc[i][j] = fmaf(a[i], b[j], acc[i][j]);
        }
        __syncthreads();
    }
    #pragma unroll
    for (int i = 0; i < TM; ++i) {
        int gm = m0 + mloc + i;
        if (gm >= M) continue;
        int br, r;
        if (BATCHED)      { br = bz; r = gm; }
        else if (NBF > 0) { br = gm / NBF; r = gm - br * NBF; }
        else              { br = 0;  r = gm; }
        const size_t crow = (size_t)br * cb + (size_t)r * cm;
        #pragma unroll
        for (int j = 0; j < TN; ++j) {
            int gn = n0 + nloc + j;
            if (gn >= Nn) continue;
            float v = acc[i][j];
            if (bias) v += bias[gn];
            size_t ci = crow + gn;
            if (Dadd) v += Dadd[ci];
            if (ACT == 1) v = fast_tanh(v);
            C[ci] = v;
        }
    }
}

// img branch tail
__global__ __launch_bounds__(256) void img_branch_kernel(
    const float* __restrict__ ih,
    const float* __restrict__ wia, const float* __restrict__ bia,
    const float* __restrict__ img_feat,
    float* __restrict__ out)
{
    const int b = blockIdx.x;
    const int t = threadIdx.x;
    const int w = t >> 6, l = t & 63;
    __shared__ float s_w[512];
    __shared__ __align__(16) float sc[200];
    __shared__ float red[8];

    for (int i = t; i < 512; i += 256) s_w[i] = wia[i];
    __syncthreads();

    const float* ihb = ih + (size_t)b * 196 * 512;
    for (int n = w; n < 196; n += 4) {
        const float* row = ihb + n * 512;
        float p = 0.f;
        for (int k = l; k < 512; k += 64) p = fmaf(s_w[k], row[k], p);
        #pragma unroll
        for (int off = 32; off > 0; off >>= 1) p += __shfl_xor(p, off);
        if (l == 0) sc[n] = p + bia[0];
    }
    __syncthreads();

    float v = (t < 196) ? sc[t] : -3.402823466e38f;
    float m = v;
    #pragma unroll
    for (int off = 32; off > 0; off >>= 1) m = fmaxf(m, __shfl_xor(m, off));
    if (l == 0) red[w] = m;
    __syncthreads();
    if (t == 0) {
        float mm = red[0];
        for (int i = 1; i < 4; ++i) mm = fmaxf(mm, red[i]);
        red[4] = mm;
    }
    __syncthreads();
    float mx = red[4];
    float e = (t < 196) ? __expf(v - mx) : 0.f;
    float s = e;
    #pragma unroll
    for (int off = 32; off > 0; off >>= 1) s += __shfl_xor(s, off);
    if (l == 0) red[w] = s;
    __syncthreads();
    if (t == 0) red[5] = 1.f / (red[0] + red[1] + red[2] + red[3]);
    __syncthreads();
    if (t < 196) sc[t] = e * red[5];
    __syncthreads();

    const float* ifb = img_feat + (size_t)b * 1024 * 196;
    for (int e0 = t; e0 < 1024; e0 += 256) {
        const float4* row = (const float4*)(ifb + (size_t)e0 * 196);
        float acc = 0.f;
        #pragma unroll 7
        for (int n4 = 0; n4 < 49; ++n4) {
            float4 x = row[n4];
            float4 a = *(const float4*)&sc[n4 * 4];
            acc = fmaf(x.x, a.x, acc);
            acc = fmaf(x.y, a.y, acc);
            acc = fmaf(x.z, a.z, acc);
            acc = fmaf(x.w, a.w, acc);
        }
        out[(size_t)b * 1024 + e0] = acc;
    }
}

// ques branch tail
__global__ __launch_bounds__(256) void ques_branch_kernel(
    const float* __restrict__ qh,
    const float* __restrict__ wqa, const float* __restrict__ bqa,
    const float* __restrict__ mask,
    const float* __restrict__ qf,
    float* __restrict__ out)
{
    const int b = blockIdx.x;
    const int t = threadIdx.x;
    const int w = t >> 6, l = t & 63;
    __shared__ float s_w[512];
    __shared__ float sq[64];

    for (int i = t; i < 512; i += 256) s_w[i] = wqa[i];
    __syncthreads();

    const float* qhb = qh + (size_t)b * 64 * 512;
    for (int q = w; q < 64; q += 4) {
        const float* row = qhb + q * 512;
        float p = 0.f;
        for (int k = l; k < 512; k += 64) p = fmaf(s_w[k], row[k], p);
        #pragma unroll
        for (int off = 32; off > 0; off >>= 1) p += __shfl_xor(p, off);
        if (l == 0) sq[q] = (p + bqa[0]) * mask[b * 64 + q];
    }
    __syncthreads();

    if (w == 0) {
        float v = sq[l];
        float m = v;
        #pragma unroll
        for (int off = 32; off > 0; off >>= 1) m = fmaxf(m, __shfl_xor(m, off));
        float e = __expf(v - m);
        float s = e;
        #pragma unroll
        for (int off = 32; off > 0; off >>= 1) s += __shfl_xor(s, off);
        sq[l] = e / s;
    }
    __syncthreads();

    const float* qfb = qf + (size_t)b * 64 * 1024;
    float4 acc = make_float4(0.f, 0.f, 0.f, 0.f);
    for (int q = 0; q < 64; ++q) {
        float a = sq[q];
        float4 x = *(const float4*)(qfb + q * 1024 + t * 4);
        acc.x = fmaf(a, x.x, acc.x);
        acc.y = fmaf(a, x.y, acc.y);
        acc.z = fmaf(a, x.z, acc.z);
        acc.w = fmaf(a, x.w, acc.w);
    }
    *(float4*)(out + (size_t)b * 1024 + t * 4) = acc;
}

extern "C" void kernel_launch(void* const* d_in, const int* in_sizes, int n_in,
                              void* d_out, int out_size, void* d_ws, size_t ws_size,
                              hipStream_t stream) {
    const float* qf  = (const float*)d_in[0];
    const float* imf = (const float*)d_in[1];
    const float* msk = (const float*)d_in[2];
    const float* Wc  = (const float*)d_in[3];
    const float* bc  = (const float*)d_in[4];
    const float* Wq  = (const float*)d_in[5];
    const float* bq  = (const float*)d_in[6];
    const float* Wi  = (const float*)d_in[7];
    const float* bi  = (const float*)d_in[8];
    const float* wqa = (const float*)d_in[9];
    const float* bqa = (const float*)d_in[10];
    const float* wia = (const float*)d_in[11];
    const float* bia = (const float*)d_in[12];
    float* out = (float*)d_out;

    const size_t perBatchF = 379136ull;
    int CB = 256;
    while (CB > 1 && (size_t)CB * perBatchF * 4ull > ws_size) CB >>= 1;

    float* ws = (float*)d_ws;
    float* qe = ws;
    float* ic = qe + (size_t)CB * 32768;
    float* ie = ic + (size_t)CB * 200704;
    float* wt = ie + (size_t)CB * 100352;
    float* qh = wt + (size_t)CB * 12544;

    dim3 blk(256);
    auto cdiv = [](int a, int b) { return (a + b - 1) / b; };

    for (int c0 = 0; c0 < 256; c0 += CB) {
        const float* qfc  = qf  + (size_t)c0 * 65536;
        const float* imfc = imf + (size_t)c0 * 200704;
        const float* mskc = msk + (size_t)c0 * 64;
        float* outq = out + (size_t)c0 * 1024;
        float* outi = out + 262144 + (size_t)c0 * 1024;

        // G1: ques_embed = Q @ Wq + bq  (MFMA)
        hipLaunchKernelGGL((mfma_gemm<0>), dim3(4, cdiv(CB * 64, 128)), blk, 0, stream,
            qfc, Wq, bq, qe, CB * 64, 512, 1024, 1024, 0);

        // G2: img_corr = img_t @ Wc + bc  (MFMA, folded m-contig A)
        hipLaunchKernelGGL((mfma_gemm<196>), dim3(8, cdiv(CB * 196, 128)), blk, 0, stream,
            imfc, Wc, bc, ic, CB * 196, 1024, 1024, 0, 200704);

        // G3: img_embed = img_t @ Wi + bi  (MFMA)
        hipLaunchKernelGGL((mfma_gemm<196>), dim3(4, cdiv(CB * 196, 128)), blk, 0, stream,
            imfc, Wi, bi, ie, CB * 196, 512, 1024, 0, 200704);

        // G4: weight[b,q,n] = tanh(Q @ img_corr^T)  batched NT (fp32)
        hipLaunchKernelGGL((gemm_k<64,64,16,4,4,0,1,0,1,true>),
            dim3(4, 1, CB), blk, 0, stream,
            qfc, ic, (const float*)nullptr, (const float*)nullptr, wt,
            64, 196, 1024,  65536,1024,1,  200704,1,1024,  12544,196);

        // G5a: img_h = tanh(weight^T @ qe + img_embed)  (fp32, overwrites ic)
        hipLaunchKernelGGL((gemm_k<128,128,16,8,8,1,0,0,1,true>),
            dim3(4, 2, CB), blk, 0, stream,
            wt, qe, (const float*)nullptr, ie, ic,
            196, 512, 64,  12544,1,196,  32768,512,1,  100352,512);

        // G5b: img tail
        hipLaunchKernelGGL(img_branch_kernel, dim3(CB), blk, 0, stream,
            ic, wia, bia, imfc, outi);

        // G6a: ques_h = tanh(weight @ img_embed + qe)  (fp32)
        hipLaunchKernelGGL((gemm_k<64,64,16,4,4,0,0,0,1,true>),
            dim3(8, 1, CB), blk, 0, stream,
            wt, ie, (const float*)nullptr, qe, qh,
            64, 512, 196,  12544,196,1,  100352,512,1,  32768,512);

        // G6b: ques tail
        hipLaunchKernelGGL(ques_branch_kernel, dim3(CB), blk, 0, stream,
            qh, wqa, bqa, mskc, qfc, outq);
    }
}